// Round 3
// baseline (213.280 us; speedup 1.0000x reference)
//
#include <hip/hip_runtime.h>

// m13-copy shape: full-coverage grid, 2 float4s per thread per input stream
// (4 independent dwordx4 loads in flight per thread), max-occupancy blocks.
constexpr int TPB  = 256;
constexpr int TPB2 = 1024;

__device__ __forceinline__ float row_contrib(float4 pv, float4 lv, int m) {
    // Element k of float4 q has component (q+k)%3; m = q%3.
    // comp 0,1: d^2 ; comp 2: (2*min(fract(|d|), 1-fract(|d|)))^2
    const float* pp = (const float*)&pv;
    const float* ll = (const float*)&lv;
    float acc = 0.0f;
#pragma unroll
    for (int k = 0; k < 4; ++k) {
        float d = pp[k] - ll[k];
        float x = fabsf(d);
        float f = x - floorf(x);
        float t = 2.0f * fminf(f, 1.0f - f);
        bool ang = (((m + k) % 3) == 2);
        float v = ang ? t : d;
        acc = fmaf(v, v, acc);
    }
    return acc;
}

__global__ __launch_bounds__(TPB) void loss_partial_kernel(
    const float* __restrict__ pred,
    const float* __restrict__ lab,
    float* __restrict__ partial,
    long long n4,        // number of float4s
    long long n_elems)   // total float count
{
    const long long tid = (long long)blockIdx.x * blockDim.x + threadIdx.x;
    const long long S   = (long long)gridDim.x * blockDim.x;

    const float4* __restrict__ p4 = (const float4*)pred;
    const float4* __restrict__ l4 = (const float4*)lab;

    float acc = 0.0f;

    const long long q0 = tid;
    const long long q1 = tid + S;

    if (q1 < n4) {
        // Hot path (all threads for the bench shape): 4 loads in flight.
        float4 pa = p4[q0];
        float4 la = l4[q0];
        float4 pb = p4[q1];
        float4 lb = l4[q1];
        acc += row_contrib(pa, la, (int)(q0 % 3));
        acc += row_contrib(pb, lb, (int)(q1 % 3));
        // Generic continuation (never taken at bench shape).
        for (long long q = tid + 2 * S; q < n4; q += S) {
            float4 pv = p4[q];
            float4 lv = l4[q];
            acc += row_contrib(pv, lv, (int)(q % 3));
        }
    } else if (q0 < n4) {
        float4 pv = p4[q0];
        float4 lv = l4[q0];
        acc += row_contrib(pv, lv, (int)(q0 % 3));
    }

    // Scalar element tail (empty when n_elems % 4 == 0).
    const long long tail_base = n4 * 4;
    if (tid < n_elems - tail_base) {
        long long e = tail_base + tid;
        float d = pred[e] - lab[e];
        if ((int)(e % 3) == 2) {
            float x = fabsf(d);
            float f = x - floorf(x);
            d = 2.0f * fminf(f, 1.0f - f);
        }
        acc = fmaf(d, d, acc);
    }

    // Wave-64 butterfly reduce.
#pragma unroll
    for (int off = 32; off > 0; off >>= 1)
        acc += __shfl_down(acc, off, 64);

    __shared__ float s_partial[TPB / 64];
    const int lane = threadIdx.x & 63;
    const int wave = threadIdx.x >> 6;
    if (lane == 0) s_partial[wave] = acc;
    __syncthreads();

    if (threadIdx.x == 0) {
        float v = 0.0f;
#pragma unroll
        for (int w = 0; w < TPB / 64; ++w) v += s_partial[w];
        partial[blockIdx.x] = v;   // no atomics
    }
}

// Stage 2: one 1024-thread block reduces `n` partials -> out[0].
// Overwrites the 0xAA poison in d_out directly (no memset needed).
__global__ __launch_bounds__(TPB2) void reduce_partials_kernel(
    const float* __restrict__ partial, float* __restrict__ out, int n)
{
    float acc = 0.0f;
    const int n4p = n / 4;
    const float4* __restrict__ p4 = (const float4*)partial;
    for (int i = threadIdx.x; i < n4p; i += TPB2) {
        float4 v = p4[i];
        acc += (v.x + v.y) + (v.z + v.w);
    }
    for (int i = n4p * 4 + threadIdx.x; i < n; i += TPB2)
        acc += partial[i];

#pragma unroll
    for (int off = 32; off > 0; off >>= 1)
        acc += __shfl_down(acc, off, 64);

    __shared__ float s_partial[TPB2 / 64];
    const int lane = threadIdx.x & 63;
    const int wave = threadIdx.x >> 6;
    if (lane == 0) s_partial[wave] = acc;
    __syncthreads();

    if (threadIdx.x == 0) {
        float v = 0.0f;
#pragma unroll
        for (int w = 0; w < TPB2 / 64; ++w) v += s_partial[w];
        out[0] = v;
    }
}

extern "C" void kernel_launch(void* const* d_in, const int* in_sizes, int n_in,
                              void* d_out, int out_size, void* d_ws, size_t ws_size,
                              hipStream_t stream) {
    const float* pred = (const float*)d_in[0];
    const float* lab  = (const float*)d_in[1];
    float* out = (float*)d_out;
    float* partial = (float*)d_ws;

    long long n_elems = (long long)in_sizes[0];   // 25165824
    long long n4 = n_elems / 4;                   // 6291456

    // Grid sized so each thread handles (up to) 2 float4s per input.
    int blocks = (int)((n4 + 2LL * TPB - 1) / (2LL * TPB));   // 12288
    if (blocks < 1) blocks = 1;

    loss_partial_kernel<<<blocks, TPB, 0, stream>>>(pred, lab, partial, n4, n_elems);
    reduce_partials_kernel<<<1, TPB2, 0, stream>>>(partial, out, blocks);
}